// Round 10
// baseline (677.290 us; speedup 1.0000x reference)
//
#include <hip/hip_runtime.h>
#include <hip/hip_fp16.h>
#include <cstdint>
#include <cstddef>

typedef __attribute__((ext_vector_type(8))) short short8;
typedef __attribute__((ext_vector_type(8))) _Float16 half8;
typedef __attribute__((ext_vector_type(16))) float f32x16;

__device__ __forceinline__ float bf2f(unsigned short u) { return __uint_as_float(((unsigned)u) << 16); }
__device__ __forceinline__ unsigned short f2bf(float f) {
    unsigned u = __float_as_uint(f);
    return (unsigned short)((u + 0x7fffu + ((u >> 16) & 1u)) >> 16);
}
// CK-style: drain LDS counters only, leave vmcnt live across the barrier
__device__ __forceinline__ void sync_lds() {
    asm volatile("s_waitcnt lgkmcnt(0)\n\ts_barrier" ::: "memory");
}
// T3-minimum: drain vmcnt (gload_lds completions) then barrier
__device__ __forceinline__ void sync_vm() {
    asm volatile("s_waitcnt vmcnt(0)\n\ts_barrier" ::: "memory");
}
// async global->LDS, 16B per lane (dest = wave-uniform base + lane*16)
__device__ __forceinline__ void gload16(const unsigned short* g, char* l) {
    __builtin_amdgcn_global_load_lds(
        (const __attribute__((address_space(1))) unsigned int*)g,
        (__attribute__((address_space(3))) unsigned int*)l, 16, 0, 0);
}

static constexpr float BN_INV = 0.9999950000374997f;  // 1/sqrt(1+1e-5)

// =====================================================================================
// Voxelize pipeline: bin -> sort -> LDS f32 accumulate. No global atomics on the grid.
// =====================================================================================

__device__ __forceinline__ int vox_bucket(float4 p, bool& ok) {
    ok = !(p.x < -32.f || p.x > 32.f || p.y < -32.f || p.y > 32.f || p.z < -32.f || p.z > 32.f);
    int cy = min(max((int)floorf((p.y + 32.f) * 2.f), 0), 127);
    int cz = min(max((int)floorf((p.z + 32.f) * 2.f), 0), 127);
    return cz * 4 + (cy >> 5);
}

__global__ __launch_bounds__(256) void vox_count(const float4* __restrict__ pts,
                                                 int* __restrict__ cnt, int N) {
    __shared__ int h[512];
    for (int t = threadIdx.x; t < 512; t += 256) h[t] = 0;
    __syncthreads();
    int stride = gridDim.x * 256;
    for (int i = blockIdx.x * 256 + threadIdx.x; i < N; i += stride) {
        float4 p = pts[i];
        bool ok;
        int bk = vox_bucket(p, ok);
        if (ok) atomicAdd(&h[bk], 1);
    }
    __syncthreads();
    for (int t = threadIdx.x; t < 512; t += 256)
        if (h[t]) atomicAdd(&cnt[t], h[t]);
}

__global__ void vox_scan(const int* __restrict__ cnt, int* __restrict__ off,
                         int* __restrict__ cur) {
    __shared__ int c[512];
    int t = threadIdx.x;  // 512 threads
    c[t] = cnt[t];
    __syncthreads();
    int s = 0;
    for (int i = 0; i < t; ++i) s += c[i];
    off[t] = s;
    cur[t] = s;
}

__global__ __launch_bounds__(256) void vox_scatter(const float4* __restrict__ pts,
                                                   int* __restrict__ cur,
                                                   float4* __restrict__ sorted, int N) {
    __shared__ int h[512];
    __shared__ int base[512];
    int b0 = blockIdx.x * 4096;
    for (int t = threadIdx.x; t < 512; t += 256) h[t] = 0;
    __syncthreads();
    float4 p[16];
    int bk[16];
#pragma unroll
    for (int j = 0; j < 16; ++j) {
        int i = b0 + j * 256 + threadIdx.x;
        bk[j] = -1;
        if (i < N) {
            p[j] = pts[i];
            bool ok;
            int b = vox_bucket(p[j], ok);
            if (ok) {
                bk[j] = b;
                atomicAdd(&h[b], 1);
            }
        }
    }
    __syncthreads();
    for (int t = threadIdx.x; t < 512; t += 256) {
        int n = h[t];
        base[t] = n ? atomicAdd(&cur[t], n) : 0;
        h[t] = 0;  // reuse as rank counter
    }
    __syncthreads();
#pragma unroll
    for (int j = 0; j < 16; ++j) {
        if (bk[j] >= 0) {
            int r = atomicAdd(&h[bk[j]], 1);
            sorted[base[bk[j]] + r] = p[j];
        }
    }
}

__global__ __launch_bounds__(256) void vox_accum(const float4* __restrict__ sorted,
                                                 const int* __restrict__ off,
                                                 const int* __restrict__ cnt,
                                                 __half2* __restrict__ grid) {
    __shared__ float s[32 * 128 * 4];  // 65536 B
    for (int t = threadIdx.x; t < 16384; t += 256) s[t] = 0.f;
    __syncthreads();
    int bid = blockIdx.x;
    int bz = bid >> 2;
    int ylo = (bid & 3) << 5;
    int b = off[bid], n = cnt[bid];
    for (int i = threadIdx.x; i < n; i += 256) {
        float4 p = sorted[b + i];
        int cx = min(max((int)floorf((p.x + 32.f) * 2.f), 0), 127);
        int cy = min(max((int)floorf((p.y + 32.f) * 2.f), 0), 127);
        float* v = s + ((cy - ylo) * 128 + cx) * 4;
        unsafeAtomicAdd(v + 0, p.x);
        unsafeAtomicAdd(v + 1, p.y);
        unsafeAtomicAdd(v + 2, p.z);
        unsafeAtomicAdd(v + 3, p.w);
    }
    __syncthreads();
    for (int t = threadIdx.x; t < 4096; t += 256) {
        int ry = t >> 7, cx = t & 127;
        const float* v = s + t * 4;
        union { __half2 h[2]; float2 f; } u;
        u.h[0] = __floats2half2_rn(v[0], v[1]);
        u.h[1] = __floats2half2_rn(v[2], v[3]);
        int gi = (((bz + 1) * 130 + (ylo + ry + 1)) * 130 + (cx + 1)) * 2;
        *(float2*)(grid + gi) = u.f;
    }
}

// ---------------- pad shell zeroing: replaces full-buffer memsets (verified R9) ----------------
__global__ __launch_bounds__(256) void pad_zero(unsigned short* __restrict__ buf,
                                                int Xp, int Zp, int C) {
    const int cpc = (C >= 8) ? (C / 8) : 1;
    long i = (long)blockIdx.x * 256 + threadIdx.x;
    long nz = (long)2 * Xp * Xp;
    long ny = (long)(Zp - 2) * 2 * Xp;
    long nx = (long)(Zp - 2) * (Xp - 2) * 2;
    long total = (nz + ny + nx) * cpc;
    if (i >= total) return;
    long cell = i / cpc;
    int ch = (int)(i - cell * cpc) * 8;
    int z, y, x;
    if (cell < nz) {
        long r = cell;
        z = (r >= (long)Xp * Xp) ? (Zp - 1) : 0;
        r %= (long)Xp * Xp;
        y = (int)(r / Xp);
        x = (int)(r % Xp);
    } else if (cell < nz + ny) {
        long r = cell - nz;
        z = 1 + (int)(r / (2 * Xp));
        int s = (int)(r % (2 * Xp));
        y = (s >= Xp) ? (Xp - 1) : 0;
        x = (s >= Xp) ? (s - Xp) : s;
    } else {
        long r = cell - nz - ny;
        z = 1 + (int)(r / ((Xp - 2) * 2));
        int s = (int)(r % ((Xp - 2) * 2));
        y = 1 + (s >> 1);
        x = (s & 1) ? (Xp - 1) : 0;
    }
    unsigned short* p = buf + (((long)z * Xp + y) * Xp + x) * C + ch;
    if (C >= 8) {
        *(short8*)p = (short8){0, 0, 0, 0, 0, 0, 0, 0};
    } else {
        *(float2*)p = (float2){0.f, 0.f};
    }
}
static inline int pad_blocks(int Xp, int Zp, int C) {
    long cells = (long)2 * Xp * Xp + (long)(Zp - 2) * 2 * Xp + (long)(Zp - 2) * (Xp - 2) * 2;
    long thr = cells * ((C >= 8) ? (C / 8) : 1);
    return (int)((thr + 255) / 256);
}

// ---------------- weight repacks (fold BN gamma scale) ----------------
__global__ __launch_bounds__(256) void repack_w(const float* __restrict__ w, const float* __restrict__ g,
                                                unsigned short* __restrict__ o, int Co, int CI) {
    int i = blockIdx.x * 256 + threadIdx.x;
    int total = 27 * Co * CI;
    if (i >= total) return;
    int ci = i % CI;
    int t = i / CI;
    int co = t % Co;
    int k = t / Co;
    float v = w[((size_t)(co * CI + ci)) * 27 + k] * g[co] * BN_INV;
    o[i] = f2bf(v);
}
// conv1 MFMA: out[pair p(9)][co(32)][k16] f16, k16 = dx*4+ci for k16<12 else 0
__global__ __launch_bounds__(256) void repack_w1m(const float* __restrict__ w, const float* __restrict__ g,
                                                  unsigned short* __restrict__ o) {
    int i = blockIdx.x * 256 + threadIdx.x;
    if (i >= 9 * 32 * 16) return;
    int k16 = i & 15;
    int co = (i >> 4) & 31;
    int p = i >> 9;
    float v = 0.f;
    if (k16 < 12) {
        int dx = k16 >> 2, ci = k16 & 3;
        int dz = p / 3, dy = p % 3;
        v = w[(co * 4 + ci) * 27 + dz * 9 + dy * 3 + dx] * g[co] * BN_INV;
    }
    o[i] = __half_as_ushort(__float2half(v));
}

// ---------------- conv1 via MFMA 32x32x16_f16, all 27 fragment loads preissued ----------------
__global__ __launch_bounds__(256) void conv1_mfma(
    const unsigned short* __restrict__ in, const unsigned short* __restrict__ wa,
    const float* __restrict__ beta, unsigned short* __restrict__ out,
    int zstart, int r0) {
    const int tid = threadIdx.x;
    const int l31 = tid & 31;
    const int lh = (tid >> 5) & 1;
    const int wv = tid >> 6;
    int v = blockIdx.x * 128 + wv * 32 + l31;
    int x = v & 127;
    int y = (v >> 7) & 127;
    int z = zstart + (v >> 14);

    const unsigned short* base = in + ((z * 130 + y) * 130 + x) * 4 + lh * 8;
    uint2 d0[9], d1[9];
    half8 a[9];
#pragma unroll
    for (int p = 0; p < 9; ++p) {
        int dz = p / 3, dy = p % 3;
        const unsigned short* rp = base + (dz * 130 + dy) * 520;
        d0[p] = *(const uint2*)(rp);
        d1[p] = *(const uint2*)(rp + 4);  // lh=1: k12-15 garbage, annihilated by A zeros
        a[p] = *(const half8*)(wa + (p * 32 + l31) * 16 + lh * 8);
    }
    f32x16 acc = {0.f};
#pragma unroll
    for (int p = 0; p < 9; ++p) {
        uint4 braw = {d0[p].x, d0[p].y, d1[p].x, d1[p].y};
        half8 b = *(half8*)&braw;
        acc = __builtin_amdgcn_mfma_f32_32x32x16_f16(a[p], b, acc, 0, 0, 0);
    }
    int r = z - zstart + r0;
    int ob = ((r * 130 + (y + 1)) * 130 + (x + 1)) * 32;
#pragma unroll
    for (int g = 0; g < 4; ++g) {
        int cb = 4 * lh + 8 * g;
        float4 bt = *(const float4*)(beta + cb);
        ushort4 u;
        u.x = f2bf(fmaxf(acc[g * 4 + 0] + bt.x, 0.f));
        u.y = f2bf(fmaxf(acc[g * 4 + 1] + bt.y, 0.f));
        u.z = f2bf(fmaxf(acc[g * 4 + 2] + bt.z, 0.f));
        u.w = f2bf(fmaxf(acc[g * 4 + 3] + bt.w, 0.f));
        *(ushort4*)(out + ob + cb) = u;
    }
}

// ---------------- conv2: R5/R9 reg-staged path (KC=32), unchanged ----------------
template <int CI, int KC, int S>
__global__ __launch_bounds__(256) void conv_mfma(
    const unsigned short* __restrict__ in, const unsigned short* __restrict__ wb,
    const float* __restrict__ beta, unsigned short* __restrict__ out,
    int D, int lgD, int Xp, int Xpo, int Co, int zin_base, int v_off) {

    constexpr int KCp = KC + 8;
    constexpr int OPB = KC / 8;
    constexpr int NB = KC / 16;
    constexpr int NA = KC / 32;
    constexpr int NCH = KC / 16;
    constexpr int NCC = CI / KC;
    constexpr int STOT = 27 * NCC;

    __shared__ __align__(16) short sA[2 * 64 * KCp];
    __shared__ __align__(16) short sB[2 * 128 * KCp];

    const int tid = threadIdx.x;
    const int l31 = tid & 31;
    const int lh = (tid >> 5) & 1;
    const int wv = tid >> 6;

    const unsigned gx = gridDim.x;
    const unsigned lin = blockIdx.y * gx + blockIdx.x;
    const unsigned q = (gx * gridDim.y) >> 3;
    const unsigned lin2 = (lin & 7) * q + (lin >> 3);
    const unsigned bxs = lin2 % gx;
    const unsigned bys = lin2 / gx;
    const int co0 = bxs * 64;

    int bgIdx[NB], blB[NB];
#pragma unroll
    for (int j = 0; j < NB; ++j) {
        int idx = tid + j * 256;
        int vL = idx / OPB;
        int oct = idx - vL * OPB;
        int vg = v_off + bys * 128 + vL;
        int x = vg & (D - 1);
        int ry = vg >> lgD;
        int y = ry & (D - 1);
        int z = ry >> lgD;
        bgIdx[j] = ((z * S * Xp + y * S) * Xp + x * S) * CI + oct * 8;
        blB[j] = vL * KCp + oct * 8;
    }
    int agIdx[NA], alA[NA];
#pragma unroll
    for (int j = 0; j < NA; ++j) {
        int idx = tid + j * 256;
        int cA = idx / OPB;
        int oct = idx - cA * OPB;
        agIdx[j] = (co0 + cA) * CI + oct * 8;
        alA[j] = cA * KCp + oct * 8;
    }
    const int bfr = (wv * 32 + l31) * KCp + lh * 8;
    const int afr = l31 * KCp + lh * 8;

    short8 rB[2][NB], rA[2][NA];

    auto loadStage = [&](int s, int r) {
        int k = s / NCC;
        int c0 = (s - k * NCC) * KC;
        int dz = k / 9;
        int rr = k - dz * 9;
        int dy = rr / 3;
        int dx = rr - dy * 3;
        int kb = (((dz - zin_base) * Xp + dy) * Xp + dx) * CI + c0;
        int ka = k * Co * CI + c0;
#pragma unroll
        for (int j = 0; j < NB; ++j) rB[r][j] = *(const short8*)(in + bgIdx[j] + kb);
#pragma unroll
        for (int j = 0; j < NA; ++j) rA[r][j] = *(const short8*)(wb + agIdx[j] + ka);
    };
    auto storeLDS = [&](int r, int buf) {
#pragma unroll
        for (int j = 0; j < NB; ++j) *(short8*)(sB + buf * 128 * KCp + blB[j]) = rB[r][j];
#pragma unroll
        for (int j = 0; j < NA; ++j) *(short8*)(sA + buf * 64 * KCp + alA[j]) = rA[r][j];
    };

    f32x16 acc0 = {0.f}, acc1 = {0.f};

    loadStage(0, 0);
    loadStage(1, 1);
    storeLDS(0, 0);
    sync_lds();

#pragma unroll
    for (int s = 0; s < STOT; ++s) {
        if (s + 2 < STOT) loadStage(s + 2, s & 1);
        const short* pB = sB + (s & 1) * 128 * KCp + bfr;
        const short* pA = sA + (s & 1) * 64 * KCp + afr;
#pragma unroll
        for (int c = 0; c < NCH; ++c) {
            short8 bv = *(const short8*)(pB + c * 16);
            short8 a0 = *(const short8*)(pA + c * 16);
            short8 a1 = *(const short8*)(pA + 32 * KCp + c * 16);
            acc0 = __builtin_amdgcn_mfma_f32_32x32x16_bf16(a0, bv, acc0, 0, 0, 0);
            acc1 = __builtin_amdgcn_mfma_f32_32x32x16_bf16(a1, bv, acc1, 0, 0, 0);
        }
        if (s + 1 < STOT) {
            storeLDS((s + 1) & 1, (s + 1) & 1);
            sync_lds();
        }
    }

    int vg = v_off + bys * 128 + wv * 32 + l31;
    int x = vg & (D - 1);
    int ry = vg >> lgD;
    int y = ry & (D - 1);
    int z = ry >> lgD;
    size_t ob = (((size_t)(z + 1) * Xpo + (y + 1)) * Xpo + (x + 1)) * Co + co0;
#pragma unroll
    for (int cot = 0; cot < 2; ++cot) {
        const f32x16& a = cot ? acc1 : acc0;
#pragma unroll
        for (int g = 0; g < 4; ++g) {
            int cb = cot * 32 + 4 * lh + 8 * g;
            float4 bt = *(const float4*)(beta + co0 + cb);
            ushort4 u;
            u.x = f2bf(fmaxf(a[g * 4 + 0] + bt.x, 0.f));
            u.y = f2bf(fmaxf(a[g * 4 + 1] + bt.y, 0.f));
            u.z = f2bf(fmaxf(a[g * 4 + 2] + bt.z, 0.f));
            u.w = f2bf(fmaxf(a[g * 4 + 3] + bt.w, 0.f));
            *(ushort4*)(out + ob + cb) = u;
        }
    }
}

// ---------------- convs 3-6: global_load_lds staging + XOR-swizzled linear LDS ----------------
// T3-minimum 2-phase (guide §5.5): per stage, issue 6 global_load_lds (4 B + 2 A, width=16)
// into the other buffer, compute current stage from LDS, single vmcnt(0)+barrier.
// gload_lds writes linearly (wave base + lane*16) -> LDS rows are linear 128B; bank safety
// via XOR oct-swizzle applied BOTH on the pre-swizzled per-lane global source
// (oct_src = (l&7)^(l>>3)) and on the fragment read (oct_lds = (2c+lh)^(row&7)) — rule #21
// "both sides or neither", involution verified on concrete lanes. b128 bank aliasing equals
// the old padded layout (measured CONFLICT=0). Eliminates reg round-trip, ds_writes and the
// lgkm drain (m151: 646 -> 874 TF for this exact staging change at a 128^2 tile).
// LDS 49152 B -> 3 blocks/CU. Accumulation chunk order unchanged -> bit-identical output.
template <int CI, int S>
__global__ __launch_bounds__(256, 3) void conv_mfma_g(
    const unsigned short* __restrict__ in, const unsigned short* __restrict__ wb,
    const float* __restrict__ beta, unsigned short* __restrict__ out,
    int D, int lgD, int Xp, int Xpo, int Co, int zin_base, int v_off) {

    constexpr int KC = 64;           // K-chunk per stage; LDS row = 128 B
    constexpr int NCC = CI / KC;
    constexpr int STOT = 27 * NCC;

    __shared__ __align__(16) char sB[2 * 128 * 128];  // 32768 B (2 bufs x 128 vox x 128B)
    __shared__ __align__(16) char sA[2 * 64 * 128];   // 16384 B (2 bufs x 64 co x 128B)

    const int tid = threadIdx.x;
    const int l31 = tid & 31;
    const int lh = (tid >> 5) & 1;
    const int wv = tid >> 6;
    const int l63 = tid & 63;

    // XCD-chunked bijective swizzle (all conv grids have nblocks % 8 == 0)
    const unsigned gx = gridDim.x;
    const unsigned lin = blockIdx.y * gx + blockIdx.x;
    const unsigned q = (gx * gridDim.y) >> 3;
    const unsigned lin2 = (lin & 7) * q + (lin >> 3);
    const unsigned bxs = lin2 % gx;
    const unsigned bys = lin2 / gx;
    const int co0 = bxs * 64;

    // pre-swizzled per-lane source oct: lane l fills LDS (row slot*8 + l>>3, oct l&7),
    // which must hold global oct (l&7)^(l>>3)
    const int swoct = (l63 & 7) ^ (l63 >> 3);

    // B source bases: issue j covers rows (j*4+wv)*8 .. +7
    int bgIdxG[4];
#pragma unroll
    for (int j = 0; j < 4; ++j) {
        int r = (j * 4 + wv) * 8 + (l63 >> 3);
        int vg = v_off + bys * 128 + r;
        int x = vg & (D - 1);
        int ry = vg >> lgD;
        int y = ry & (D - 1);
        int z = ry >> lgD;
        bgIdxG[j] = ((z * S * Xp + y * S) * Xp + x * S) * CI + swoct * 8;
    }
    // A source bases: issue j covers co rows (j*4+wv)*8 .. +7
    int agIdxG[2];
#pragma unroll
    for (int j = 0; j < 2; ++j) {
        int r = (j * 4 + wv) * 8 + (l63 >> 3);
        agIdxG[j] = (co0 + r) * CI + swoct * 8;
    }

    auto issueStage = [&](int s, int buf) {
        int k = s / NCC;
        int c0 = (s - k * NCC) * KC;
        int dz = k / 9;
        int rr = k - dz * 9;
        int dy = rr / 3;
        int dx = rr - dy * 3;
        int kb = (((dz - zin_base) * Xp + dy) * Xp + dx) * CI + c0;
        int ka = k * Co * CI + c0;
#pragma unroll
        for (int j = 0; j < 4; ++j)
            gload16(in + bgIdxG[j] + kb, sB + buf * 16384 + (j * 4 + wv) * 1024);
#pragma unroll
        for (int j = 0; j < 2; ++j)
            gload16(wb + agIdxG[j] + ka, sA + buf * 8192 + (j * 4 + wv) * 1024);
    };

    // fragment read offsets (swizzled): row r, k-chunk c, half lh ->
    // byte = r*128 + ((2c+lh)^(r&7))*16
    const int brow = wv * 32 + l31;
    const int r7 = l31 & 7;  // == brow&7 == arow&7 (both a0/a1 rows share l31&7)

    f32x16 acc0 = {0.f}, acc1 = {0.f};

    issueStage(0, 0);
    sync_vm();

#pragma unroll
    for (int s = 0; s < STOT; ++s) {
        if (s + 1 < STOT) issueStage(s + 1, (s + 1) & 1);
        const char* pB = sB + (s & 1) * 16384 + brow * 128;
        const char* pA0 = sA + (s & 1) * 8192 + l31 * 128;
        const char* pA1 = pA0 + 32 * 128;
#pragma unroll
        for (int c = 0; c < 4; ++c) {
            int oct = ((2 * c + lh) ^ r7) * 16;
            short8 bv = *(const short8*)(pB + oct);
            short8 a0 = *(const short8*)(pA0 + oct);
            short8 a1 = *(const short8*)(pA1 + oct);
            acc0 = __builtin_amdgcn_mfma_f32_32x32x16_bf16(a0, bv, acc0, 0, 0, 0);
            acc1 = __builtin_amdgcn_mfma_f32_32x32x16_bf16(a1, bv, acc1, 0, 0, 0);
        }
        sync_vm();  // next-stage loads (issued above) drained; all waves done reading
    }

    // epilogue: relu(acc + beta) -> bf16, channels-last padded store (layout verified R4)
    int vg = v_off + bys * 128 + wv * 32 + l31;
    int x = vg & (D - 1);
    int ry = vg >> lgD;
    int y = ry & (D - 1);
    int z = ry >> lgD;
    size_t ob = (((size_t)(z + 1) * Xpo + (y + 1)) * Xpo + (x + 1)) * Co + co0;
#pragma unroll
    for (int cot = 0; cot < 2; ++cot) {
        const f32x16& a = cot ? acc1 : acc0;
#pragma unroll
        for (int g = 0; g < 4; ++g) {
            int cb = cot * 32 + 4 * lh + 8 * g;
            float4 bt = *(const float4*)(beta + co0 + cb);
            ushort4 u;
            u.x = f2bf(fmaxf(a[g * 4 + 0] + bt.x, 0.f));
            u.y = f2bf(fmaxf(a[g * 4 + 1] + bt.y, 0.f));
            u.z = f2bf(fmaxf(a[g * 4 + 2] + bt.z, 0.f));
            u.w = f2bf(fmaxf(a[g * 4 + 3] + bt.w, 0.f));
            *(ushort4*)(out + ob + cb) = u;
        }
    }
}

// ---------------- BEV max over y: O6p (34,34,34,256) -> bev[(z*32+x)*256+c] f32 ----------------
__global__ __launch_bounds__(256) void bev_max_kernel(const unsigned short* __restrict__ feat,
                                                      float* __restrict__ bev) {
    int z = blockIdx.x >> 5;
    int x = blockIdx.x & 31;
    int c = threadIdx.x;
    const unsigned short* p = feat + ((((z + 1) * 34) + 1) * 34 + (x + 1)) * 256 + c;
    float mx = 0.f;  // post-ReLU values are >= 0
#pragma unroll
    for (int y = 0; y < 32; ++y) mx = fmaxf(mx, bf2f(p[y * 34 * 256]));
    bev[(z * 32 + x) * 256 + c] = mx;
}

// ---------------- bilinear resize 32x32 -> 200x200, half-pixel, edge clamp ----------------
__global__ __launch_bounds__(256) void resize_kernel(const float* __restrict__ bev,
                                                     float* __restrict__ out) {
    int i = blockIdx.x * 256 + threadIdx.x;
    if (i >= 256 * 200 * 200) return;
    int ox = i % 200;
    int t = i / 200;
    int oy = t % 200;
    int c = t / 200;
    const float sc = 32.0f / 200.0f;
    float fy = (oy + 0.5f) * sc - 0.5f;
    float fx = (ox + 0.5f) * sc - 0.5f;
    float fy0 = floorf(fy), fx0 = floorf(fx);
    float ty = fy - fy0, tx = fx - fx0;
    int y0 = min(max((int)fy0, 0), 31), y1 = min(max((int)fy0 + 1, 0), 31);
    int x0 = min(max((int)fx0, 0), 31), x1 = min(max((int)fx0 + 1, 0), 31);
    float v00 = bev[(y0 * 32 + x0) * 256 + c], v01 = bev[(y0 * 32 + x1) * 256 + c];
    float v10 = bev[(y1 * 32 + x0) * 256 + c], v11 = bev[(y1 * 32 + x1) * 256 + c];
    float top = v00 + tx * (v01 - v00);
    float bot = v10 + tx * (v11 - v10);
    out[i] = top + ty * (bot - top);
}

extern "C" void kernel_launch(void* const* d_in, const int* in_sizes, int n_in,
                              void* d_out, int out_size, void* d_ws, size_t ws_size,
                              hipStream_t stream) {
    const float* points = (const float*)d_in[0];
    int N = in_sizes[0] / 4;
    const float *W[6], *G[6], *B[6];
    for (int i = 0; i < 6; ++i) {
        W[i] = (const float*)d_in[1 + 3 * i];
        G[i] = (const float*)d_in[2 + 3 * i];
        B[i] = (const float*)d_in[3 + 3 * i];
    }

    // ---- workspace layout (bytes), peak ~145 MiB ----
    char* ws = (char*)d_ws;
    const size_t MiB = 1ull << 20;
    unsigned short* gridH = (unsigned short*)(ws);               // f16 (130^3,4) = 17,576,000 B
    int* cnt = (int*)(ws + 17580032);                            // 512 ints (gap before 18 MiB)
    int* off = cnt + 512;
    int* cur = off + 512;
    float4* sorted = (float4*)(ws + 18 * MiB);                   // 32 MB, dead before O1s use
    unsigned short* O1s = (unsigned short*)(ws + 18 * MiB);      // 65*130*130*32*2 = 70,304,000
    unsigned short* O2p = (unsigned short*)(ws + 104 * MiB);     // 66^3*64*2 = 36,799,488
    unsigned short* O3p = (unsigned short*)(ws);                 // 36,799,488 (over dead gridH/O1s-head)
    unsigned short* O4p = (unsigned short*)(ws + 37 * MiB);      // 34^3*128*2 = 10,061,824
    unsigned short* O5p = (unsigned short*)(ws + 48 * MiB);      // 10,061,824
    unsigned short* O6p = (unsigned short*)(ws + 59 * MiB);      // 34^3*256*2 = 20,123,648
    float* bev = (float*)(ws + 80 * MiB);                        // 1,048,576
    unsigned short* wc1 = (unsigned short*)(ws + 140 * MiB);     // 9*32*16*2 = 9,216
    unsigned short* wb2 = (unsigned short*)(ws + 140 * MiB + 16384);
    unsigned short* wb3 = wb2 + 27 * 64 * 32;
    unsigned short* wb4 = wb3 + 27 * 64 * 64;
    unsigned short* wb5 = wb4 + 27 * 128 * 64;
    unsigned short* wb6 = wb5 + 27 * 128 * 128;

    // weight repacks (independent of activations)
    repack_w1m<<<18, 256, 0, stream>>>(W[0], G[0], wc1);
    repack_w<<<216, 256, 0, stream>>>(W[1], G[1], wb2, 64, 32);
    repack_w<<<432, 256, 0, stream>>>(W[2], G[2], wb3, 64, 64);
    repack_w<<<864, 256, 0, stream>>>(W[3], G[3], wb4, 128, 64);
    repack_w<<<1728, 256, 0, stream>>>(W[4], G[4], wb5, 128, 128);
    repack_w<<<3456, 256, 0, stream>>>(W[5], G[5], wb6, 256, 128);

    // voxelize: bin -> scan -> sort -> LDS accumulate (no global atomics).
    pad_zero<<<pad_blocks(130, 130, 4), 256, 0, stream>>>(gridH, 130, 130, 4);
    hipMemsetAsync(cnt, 0, 2048, stream);
    pad_zero<<<pad_blocks(66, 66, 64), 256, 0, stream>>>(O2p, 66, 66, 64);
    vox_count<<<1024, 256, 0, stream>>>((const float4*)points, cnt, N);
    vox_scan<<<1, 512, 0, stream>>>(cnt, off, cur);
    vox_scatter<<<(N + 4095) / 4096, 256, 0, stream>>>((const float4*)points, cur, sorted, N);
    vox_accum<<<512, 256, 0, stream>>>(sorted, off, cnt, (__half2*)gridH);

    // conv1/conv2 in two z-slabs (O1s holds 65 padded-z rows); sorted is dead now.
    pad_zero<<<pad_blocks(130, 65, 32), 256, 0, stream>>>(O1s, 130, 65, 32);
    conv1_mfma<<<8192, 256, 0, stream>>>(gridH, wc1, B[0], O1s, 0, 1);
    conv_mfma<32, 32, 2><<<dim3(1, 1024), 256, 0, stream>>>(O1s, wb2, B[1], O2p, 64, 6, 130, 66, 64, 0, 0);
    conv1_mfma<<<8320, 256, 0, stream>>>(gridH, wc1, B[0], O1s, 63, 0);
    conv_mfma<32, 32, 2><<<dim3(1, 1024), 256, 0, stream>>>(O1s, wb2, B[1], O2p, 64, 6, 130, 66, 64, 64, 131072);

    // remaining buffers become free only after conv2-h2; shells only (interiors fully written)
    pad_zero<<<pad_blocks(66, 66, 64), 256, 0, stream>>>(O3p, 66, 66, 64);
    pad_zero<<<pad_blocks(34, 34, 128), 256, 0, stream>>>(O4p, 34, 34, 128);
    pad_zero<<<pad_blocks(34, 34, 128), 256, 0, stream>>>(O5p, 34, 34, 128);
    pad_zero<<<pad_blocks(34, 34, 256), 256, 0, stream>>>(O6p, 34, 34, 256);

    // conv3: 64->64, s1, 64^3  (gload_lds staging, 49152 B LDS, 3 blocks/CU)
    conv_mfma_g<64, 1><<<dim3(1, 2048), 256, 0, stream>>>(O2p, wb3, B[2], O3p, 64, 6, 66, 66, 64, 0, 0);
    // conv4: 64->128, s2, 64^3 -> 32^3
    conv_mfma_g<64, 2><<<dim3(2, 256), 256, 0, stream>>>(O3p, wb4, B[3], O4p, 32, 5, 66, 34, 128, 0, 0);
    // conv5: 128->128, s1, 32^3
    conv_mfma_g<128, 1><<<dim3(2, 256), 256, 0, stream>>>(O4p, wb5, B[4], O5p, 32, 5, 34, 34, 128, 0, 0);
    // conv6: 128->256, s1, 32^3
    conv_mfma_g<128, 1><<<dim3(4, 256), 256, 0, stream>>>(O5p, wb6, B[5], O6p, 32, 5, 34, 34, 256, 0, 0);

    bev_max_kernel<<<1024, 256, 0, stream>>>(O6p, bev);
    resize_kernel<<<40000, 256, 0, stream>>>(bev, (float*)d_out);
}

// Round 11
// 628.819 us; speedup vs baseline: 1.0771x; 1.0771x over previous
//
#include <hip/hip_runtime.h>
#include <hip/hip_fp16.h>
#include <cstdint>
#include <cstddef>

typedef __attribute__((ext_vector_type(8))) short short8;
typedef __attribute__((ext_vector_type(8))) _Float16 half8;
typedef __attribute__((ext_vector_type(16))) float f32x16;

__device__ __forceinline__ float bf2f(unsigned short u) { return __uint_as_float(((unsigned)u) << 16); }
__device__ __forceinline__ unsigned short f2bf(float f) {
    unsigned u = __float_as_uint(f);
    return (unsigned short)((u + 0x7fffu + ((u >> 16) & 1u)) >> 16);
}
// CK-style: drain LDS counters only, leave vmcnt live across the barrier
__device__ __forceinline__ void sync_lds() {
    asm volatile("s_waitcnt lgkmcnt(0)\n\ts_barrier" ::: "memory");
}

static constexpr float BN_INV = 0.9999950000374997f;  // 1/sqrt(1+1e-5)

// =====================================================================================
// Voxelize pipeline: bin -> sort -> LDS f32 accumulate. No global atomics on the grid.
// =====================================================================================

__device__ __forceinline__ int vox_bucket(float4 p, bool& ok) {
    ok = !(p.x < -32.f || p.x > 32.f || p.y < -32.f || p.y > 32.f || p.z < -32.f || p.z > 32.f);
    int cy = min(max((int)floorf((p.y + 32.f) * 2.f), 0), 127);
    int cz = min(max((int)floorf((p.z + 32.f) * 2.f), 0), 127);
    return cz * 4 + (cy >> 5);
}

__global__ __launch_bounds__(256) void vox_count(const float4* __restrict__ pts,
                                                 int* __restrict__ cnt, int N) {
    __shared__ int h[512];
    for (int t = threadIdx.x; t < 512; t += 256) h[t] = 0;
    __syncthreads();
    int stride = gridDim.x * 256;
    for (int i = blockIdx.x * 256 + threadIdx.x; i < N; i += stride) {
        float4 p = pts[i];
        bool ok;
        int bk = vox_bucket(p, ok);
        if (ok) atomicAdd(&h[bk], 1);
    }
    __syncthreads();
    for (int t = threadIdx.x; t < 512; t += 256)
        if (h[t]) atomicAdd(&cnt[t], h[t]);
}

__global__ void vox_scan(const int* __restrict__ cnt, int* __restrict__ off,
                         int* __restrict__ cur) {
    __shared__ int c[512];
    int t = threadIdx.x;  // 512 threads
    c[t] = cnt[t];
    __syncthreads();
    int s = 0;
    for (int i = 0; i < t; ++i) s += c[i];
    off[t] = s;
    cur[t] = s;
}

__global__ __launch_bounds__(256) void vox_scatter(const float4* __restrict__ pts,
                                                   int* __restrict__ cur,
                                                   float4* __restrict__ sorted, int N) {
    __shared__ int h[512];
    __shared__ int base[512];
    int b0 = blockIdx.x * 4096;
    for (int t = threadIdx.x; t < 512; t += 256) h[t] = 0;
    __syncthreads();
    float4 p[16];
    int bk[16];
#pragma unroll
    for (int j = 0; j < 16; ++j) {
        int i = b0 + j * 256 + threadIdx.x;
        bk[j] = -1;
        if (i < N) {
            p[j] = pts[i];
            bool ok;
            int b = vox_bucket(p[j], ok);
            if (ok) {
                bk[j] = b;
                atomicAdd(&h[b], 1);
            }
        }
    }
    __syncthreads();
    for (int t = threadIdx.x; t < 512; t += 256) {
        int n = h[t];
        base[t] = n ? atomicAdd(&cur[t], n) : 0;
        h[t] = 0;  // reuse as rank counter
    }
    __syncthreads();
#pragma unroll
    for (int j = 0; j < 16; ++j) {
        if (bk[j] >= 0) {
            int r = atomicAdd(&h[bk[j]], 1);
            sorted[base[bk[j]] + r] = p[j];
        }
    }
}

__global__ __launch_bounds__(256) void vox_accum(const float4* __restrict__ sorted,
                                                 const int* __restrict__ off,
                                                 const int* __restrict__ cnt,
                                                 __half2* __restrict__ grid) {
    __shared__ float s[32 * 128 * 4];  // 65536 B
    for (int t = threadIdx.x; t < 16384; t += 256) s[t] = 0.f;
    __syncthreads();
    int bid = blockIdx.x;
    int bz = bid >> 2;
    int ylo = (bid & 3) << 5;
    int b = off[bid], n = cnt[bid];
    for (int i = threadIdx.x; i < n; i += 256) {
        float4 p = sorted[b + i];
        int cx = min(max((int)floorf((p.x + 32.f) * 2.f), 0), 127);
        int cy = min(max((int)floorf((p.y + 32.f) * 2.f), 0), 127);
        float* v = s + ((cy - ylo) * 128 + cx) * 4;
        unsafeAtomicAdd(v + 0, p.x);
        unsafeAtomicAdd(v + 1, p.y);
        unsafeAtomicAdd(v + 2, p.z);
        unsafeAtomicAdd(v + 3, p.w);
    }
    __syncthreads();
    for (int t = threadIdx.x; t < 4096; t += 256) {
        int ry = t >> 7, cx = t & 127;
        const float* v = s + t * 4;
        union { __half2 h[2]; float2 f; } u;
        u.h[0] = __floats2half2_rn(v[0], v[1]);
        u.h[1] = __floats2half2_rn(v[2], v[3]);
        int gi = (((bz + 1) * 130 + (ylo + ry + 1)) * 130 + (cx + 1)) * 2;
        *(float2*)(grid + gi) = u.f;
    }
}

// ---------------- pad shell zeroing: replaces full-buffer memsets (verified R9) ----------------
__global__ __launch_bounds__(256) void pad_zero(unsigned short* __restrict__ buf,
                                                int Xp, int Zp, int C) {
    const int cpc = (C >= 8) ? (C / 8) : 1;
    long i = (long)blockIdx.x * 256 + threadIdx.x;
    long nz = (long)2 * Xp * Xp;
    long ny = (long)(Zp - 2) * 2 * Xp;
    long nx = (long)(Zp - 2) * (Xp - 2) * 2;
    long total = (nz + ny + nx) * cpc;
    if (i >= total) return;
    long cell = i / cpc;
    int ch = (int)(i - cell * cpc) * 8;
    int z, y, x;
    if (cell < nz) {
        long r = cell;
        z = (r >= (long)Xp * Xp) ? (Zp - 1) : 0;
        r %= (long)Xp * Xp;
        y = (int)(r / Xp);
        x = (int)(r % Xp);
    } else if (cell < nz + ny) {
        long r = cell - nz;
        z = 1 + (int)(r / (2 * Xp));
        int s = (int)(r % (2 * Xp));
        y = (s >= Xp) ? (Xp - 1) : 0;
        x = (s >= Xp) ? (s - Xp) : s;
    } else {
        long r = cell - nz - ny;
        z = 1 + (int)(r / ((Xp - 2) * 2));
        int s = (int)(r % ((Xp - 2) * 2));
        y = 1 + (s >> 1);
        x = (s & 1) ? (Xp - 1) : 0;
    }
    unsigned short* p = buf + (((long)z * Xp + y) * Xp + x) * C + ch;
    if (C >= 8) {
        *(short8*)p = (short8){0, 0, 0, 0, 0, 0, 0, 0};
    } else {
        *(float2*)p = (float2){0.f, 0.f};
    }
}
static inline int pad_blocks(int Xp, int Zp, int C) {
    long cells = (long)2 * Xp * Xp + (long)(Zp - 2) * 2 * Xp + (long)(Zp - 2) * (Xp - 2) * 2;
    long thr = cells * ((C >= 8) ? (C / 8) : 1);
    return (int)((thr + 255) / 256);
}

// ---------------- weight repacks (fold BN gamma scale) ----------------
__global__ __launch_bounds__(256) void repack_w(const float* __restrict__ w, const float* __restrict__ g,
                                                unsigned short* __restrict__ o, int Co, int CI) {
    int i = blockIdx.x * 256 + threadIdx.x;
    int total = 27 * Co * CI;
    if (i >= total) return;
    int ci = i % CI;
    int t = i / CI;
    int co = t % Co;
    int k = t / Co;
    float v = w[((size_t)(co * CI + ci)) * 27 + k] * g[co] * BN_INV;
    o[i] = f2bf(v);
}
// conv1 MFMA: out[pair p(9)][co(32)][k16] f16, k16 = dx*4+ci for k16<12 else 0
__global__ __launch_bounds__(256) void repack_w1m(const float* __restrict__ w, const float* __restrict__ g,
                                                  unsigned short* __restrict__ o) {
    int i = blockIdx.x * 256 + threadIdx.x;
    if (i >= 9 * 32 * 16) return;
    int k16 = i & 15;
    int co = (i >> 4) & 31;
    int p = i >> 9;
    float v = 0.f;
    if (k16 < 12) {
        int dx = k16 >> 2, ci = k16 & 3;
        int dz = p / 3, dy = p % 3;
        v = w[(co * 4 + ci) * 27 + dz * 9 + dy * 3 + dx] * g[co] * BN_INV;
    }
    o[i] = __half_as_ushort(__float2half(v));
}

// ---------------- conv1 via MFMA 32x32x16_f16, all 27 fragment loads preissued ----------------
__global__ __launch_bounds__(256) void conv1_mfma(
    const unsigned short* __restrict__ in, const unsigned short* __restrict__ wa,
    const float* __restrict__ beta, unsigned short* __restrict__ out,
    int zstart, int r0) {
    const int tid = threadIdx.x;
    const int l31 = tid & 31;
    const int lh = (tid >> 5) & 1;
    const int wv = tid >> 6;
    int v = blockIdx.x * 128 + wv * 32 + l31;
    int x = v & 127;
    int y = (v >> 7) & 127;
    int z = zstart + (v >> 14);

    const unsigned short* base = in + ((z * 130 + y) * 130 + x) * 4 + lh * 8;
    uint2 d0[9], d1[9];
    half8 a[9];
#pragma unroll
    for (int p = 0; p < 9; ++p) {
        int dz = p / 3, dy = p % 3;
        const unsigned short* rp = base + (dz * 130 + dy) * 520;
        d0[p] = *(const uint2*)(rp);
        d1[p] = *(const uint2*)(rp + 4);  // lh=1: k12-15 garbage, annihilated by A zeros
        a[p] = *(const half8*)(wa + (p * 32 + l31) * 16 + lh * 8);
    }
    f32x16 acc = {0.f};
#pragma unroll
    for (int p = 0; p < 9; ++p) {
        uint4 braw = {d0[p].x, d0[p].y, d1[p].x, d1[p].y};
        half8 b = *(half8*)&braw;
        acc = __builtin_amdgcn_mfma_f32_32x32x16_f16(a[p], b, acc, 0, 0, 0);
    }
    int r = z - zstart + r0;
    int ob = ((r * 130 + (y + 1)) * 130 + (x + 1)) * 32;
#pragma unroll
    for (int g = 0; g < 4; ++g) {
        int cb = 4 * lh + 8 * g;
        float4 bt = *(const float4*)(beta + cb);
        ushort4 u;
        u.x = f2bf(fmaxf(acc[g * 4 + 0] + bt.x, 0.f));
        u.y = f2bf(fmaxf(acc[g * 4 + 1] + bt.y, 0.f));
        u.z = f2bf(fmaxf(acc[g * 4 + 2] + bt.z, 0.f));
        u.w = f2bf(fmaxf(acc[g * 4 + 3] + bt.w, 0.f));
        *(ushort4*)(out + ob + cb) = u;
    }
}

// ---------------- convs 2-3: R9 reg-staged path (proven 87.5us conv3) ----------------
// 256 thr = 4 waves, tile 64co x 128vox; wave 64co x 32vox. Step s issues global loads for
// stage s+2 (regs), computes stage s from LDS buf s&1, dumps s+1 regs to LDS, lgkm-only
// barrier. KCp=KC+8: measured CONFLICT=0. XCD swizzle: FETCH 37->23 MB (R5).
template <int CI, int KC, int S>
__global__ __launch_bounds__(256) void conv_mfma(
    const unsigned short* __restrict__ in, const unsigned short* __restrict__ wb,
    const float* __restrict__ beta, unsigned short* __restrict__ out,
    int D, int lgD, int Xp, int Xpo, int Co, int zin_base, int v_off) {

    constexpr int KCp = KC + 8;
    constexpr int OPB = KC / 8;
    constexpr int NB = KC / 16;
    constexpr int NA = KC / 32;
    constexpr int NCH = KC / 16;
    constexpr int NCC = CI / KC;
    constexpr int STOT = 27 * NCC;

    __shared__ __align__(16) short sA[2 * 64 * KCp];
    __shared__ __align__(16) short sB[2 * 128 * KCp];

    const int tid = threadIdx.x;
    const int l31 = tid & 31;
    const int lh = (tid >> 5) & 1;
    const int wv = tid >> 6;

    const unsigned gx = gridDim.x;
    const unsigned lin = blockIdx.y * gx + blockIdx.x;
    const unsigned q = (gx * gridDim.y) >> 3;
    const unsigned lin2 = (lin & 7) * q + (lin >> 3);
    const unsigned bxs = lin2 % gx;
    const unsigned bys = lin2 / gx;
    const int co0 = bxs * 64;

    int bgIdx[NB], blB[NB];
#pragma unroll
    for (int j = 0; j < NB; ++j) {
        int idx = tid + j * 256;
        int vL = idx / OPB;
        int oct = idx - vL * OPB;
        int vg = v_off + bys * 128 + vL;
        int x = vg & (D - 1);
        int ry = vg >> lgD;
        int y = ry & (D - 1);
        int z = ry >> lgD;
        bgIdx[j] = ((z * S * Xp + y * S) * Xp + x * S) * CI + oct * 8;
        blB[j] = vL * KCp + oct * 8;
    }
    int agIdx[NA], alA[NA];
#pragma unroll
    for (int j = 0; j < NA; ++j) {
        int idx = tid + j * 256;
        int cA = idx / OPB;
        int oct = idx - cA * OPB;
        agIdx[j] = (co0 + cA) * CI + oct * 8;
        alA[j] = cA * KCp + oct * 8;
    }
    const int bfr = (wv * 32 + l31) * KCp + lh * 8;
    const int afr = l31 * KCp + lh * 8;

    short8 rB[2][NB], rA[2][NA];

    auto loadStage = [&](int s, int r) {
        int k = s / NCC;
        int c0 = (s - k * NCC) * KC;
        int dz = k / 9;
        int rr = k - dz * 9;
        int dy = rr / 3;
        int dx = rr - dy * 3;
        int kb = (((dz - zin_base) * Xp + dy) * Xp + dx) * CI + c0;
        int ka = k * Co * CI + c0;
#pragma unroll
        for (int j = 0; j < NB; ++j) rB[r][j] = *(const short8*)(in + bgIdx[j] + kb);
#pragma unroll
        for (int j = 0; j < NA; ++j) rA[r][j] = *(const short8*)(wb + agIdx[j] + ka);
    };
    auto storeLDS = [&](int r, int buf) {
#pragma unroll
        for (int j = 0; j < NB; ++j) *(short8*)(sB + buf * 128 * KCp + blB[j]) = rB[r][j];
#pragma unroll
        for (int j = 0; j < NA; ++j) *(short8*)(sA + buf * 64 * KCp + alA[j]) = rA[r][j];
    };

    f32x16 acc0 = {0.f}, acc1 = {0.f};

    loadStage(0, 0);
    loadStage(1, 1);
    storeLDS(0, 0);
    sync_lds();

#pragma unroll
    for (int s = 0; s < STOT; ++s) {
        if (s + 2 < STOT) loadStage(s + 2, s & 1);
        const short* pB = sB + (s & 1) * 128 * KCp + bfr;
        const short* pA = sA + (s & 1) * 64 * KCp + afr;
#pragma unroll
        for (int c = 0; c < NCH; ++c) {
            short8 bv = *(const short8*)(pB + c * 16);
            short8 a0 = *(const short8*)(pA + c * 16);
            short8 a1 = *(const short8*)(pA + 32 * KCp + c * 16);
            acc0 = __builtin_amdgcn_mfma_f32_32x32x16_bf16(a0, bv, acc0, 0, 0, 0);
            acc1 = __builtin_amdgcn_mfma_f32_32x32x16_bf16(a1, bv, acc1, 0, 0, 0);
        }
        if (s + 1 < STOT) {
            storeLDS((s + 1) & 1, (s + 1) & 1);
            sync_lds();
        }
    }

    int vg = v_off + bys * 128 + wv * 32 + l31;
    int x = vg & (D - 1);
    int ry = vg >> lgD;
    int y = ry & (D - 1);
    int z = ry >> lgD;
    size_t ob = (((size_t)(z + 1) * Xpo + (y + 1)) * Xpo + (x + 1)) * Co + co0;
#pragma unroll
    for (int cot = 0; cot < 2; ++cot) {
        const f32x16& a = cot ? acc1 : acc0;
#pragma unroll
        for (int g = 0; g < 4; ++g) {
            int cb = cot * 32 + 4 * lh + 8 * g;
            float4 bt = *(const float4*)(beta + co0 + cb);
            ushort4 u;
            u.x = f2bf(fmaxf(a[g * 4 + 0] + bt.x, 0.f));
            u.y = f2bf(fmaxf(a[g * 4 + 1] + bt.y, 0.f));
            u.z = f2bf(fmaxf(a[g * 4 + 2] + bt.z, 0.f));
            u.w = f2bf(fmaxf(a[g * 4 + 3] + bt.w, 0.f));
            *(ushort4*)(out + ob + cb) = u;
        }
    }
}

// ---------------- convs 4-6: wide wave tile 64co x 64vox (LDS-BW fix) ----------------
// Block 128co x 128vox, 4 waves in 2x2 (wr=co half, wc=vox half). Per k16 chunk a wave
// reads 2 A + 2 B frags and issues 4 MFMA -> LDS read traffic 1.0 KB/MFMA vs 1.5 in the
// 64x32 tile; block-stage LDS traffic drops 72->~101KB per 2x the MFMAs (2.25->1.58
// KB/MFMA). R6's failure causes removed: proven KCp=KC+8 layout (CONFLICT=0), KC=64,
// 128-vox block span (same epilogue write pattern as R9). Pipeline/accumulation order
// unchanged -> bit-identical output. LDS 73728 B -> 2 blocks/CU (same occupancy as R9).
template <int CI, int S>
__global__ __launch_bounds__(256, 2) void conv_mfma_w(
    const unsigned short* __restrict__ in, const unsigned short* __restrict__ wb,
    const float* __restrict__ beta, unsigned short* __restrict__ out,
    int D, int lgD, int Xp, int Xpo, int Co, int zin_base, int v_off) {

    constexpr int KC = 64;
    constexpr int KCp = KC + 8;      // 144 B rows, proven conflict-free
    constexpr int OPB = KC / 8;      // 8 octets per row
    constexpr int NB = 4;            // 128 rows * 8 oct / 256 thr
    constexpr int NA = 4;            // 128 co rows
    constexpr int NCH = 4;
    constexpr int NCC = CI / KC;
    constexpr int STOT = 27 * NCC;

    __shared__ __align__(16) short sA[2 * 128 * KCp];
    __shared__ __align__(16) short sB[2 * 128 * KCp];

    const int tid = threadIdx.x;
    const int l31 = tid & 31;
    const int lh = (tid >> 5) & 1;
    const int wv = tid >> 6;
    const int wr = wv >> 1;   // co half (0/1)
    const int wc = wv & 1;    // vox half (0/1)

    // XCD-chunked bijective swizzle (grids are multiples of 8)
    const unsigned gx = gridDim.x;
    const unsigned lin = blockIdx.y * gx + blockIdx.x;
    const unsigned q = (gx * gridDim.y) >> 3;
    const unsigned lin2 = (lin & 7) * q + (lin >> 3);
    const unsigned bxs = lin2 % gx;
    const unsigned bys = lin2 / gx;
    const int co0 = bxs * 128;

    // B staging addresses (128 vox rows)
    int bgIdx[NB], blB[NB];
#pragma unroll
    for (int j = 0; j < NB; ++j) {
        int idx = tid + j * 256;
        int vL = idx / OPB;
        int oct = idx - vL * OPB;
        int vg = v_off + bys * 128 + vL;
        int x = vg & (D - 1);
        int ry = vg >> lgD;
        int y = ry & (D - 1);
        int z = ry >> lgD;
        bgIdx[j] = ((z * S * Xp + y * S) * Xp + x * S) * CI + oct * 8;
        blB[j] = vL * KCp + oct * 8;
    }
    // A staging addresses (128 co rows)
    int agIdx[NA], alA[NA];
#pragma unroll
    for (int j = 0; j < NA; ++j) {
        int idx = tid + j * 256;
        int cA = idx / OPB;
        int oct = idx - cA * OPB;
        agIdx[j] = (co0 + cA) * CI + oct * 8;
        alA[j] = cA * KCp + oct * 8;
    }
    const int bfr = (wc * 64 + l31) * KCp + lh * 8;
    const int afr = (wr * 64 + l31) * KCp + lh * 8;

    short8 rB[2][NB], rA[2][NA];

    auto loadStage = [&](int s, int r) {
        int k = s / NCC;
        int c0 = (s - k * NCC) * KC;
        int dz = k / 9;
        int rr = k - dz * 9;
        int dy = rr / 3;
        int dx = rr - dy * 3;
        int kb = (((dz - zin_base) * Xp + dy) * Xp + dx) * CI + c0;
        int ka = k * Co * CI + c0;
#pragma unroll
        for (int j = 0; j < NB; ++j) rB[r][j] = *(const short8*)(in + bgIdx[j] + kb);
#pragma unroll
        for (int j = 0; j < NA; ++j) rA[r][j] = *(const short8*)(wb + agIdx[j] + ka);
    };
    auto storeLDS = [&](int r, int buf) {
#pragma unroll
        for (int j = 0; j < NB; ++j) *(short8*)(sB + buf * 128 * KCp + blB[j]) = rB[r][j];
#pragma unroll
        for (int j = 0; j < NA; ++j) *(short8*)(sA + buf * 128 * KCp + alA[j]) = rA[r][j];
    };

    f32x16 acc00 = {0.f}, acc01 = {0.f}, acc10 = {0.f}, acc11 = {0.f};

    loadStage(0, 0);
    loadStage(1, 1);
    storeLDS(0, 0);
    sync_lds();

#pragma unroll
    for (int s = 0; s < STOT; ++s) {
        if (s + 2 < STOT) loadStage(s + 2, s & 1);
        const short* pB = sB + (s & 1) * 128 * KCp + bfr;
        const short* pA = sA + (s & 1) * 128 * KCp + afr;
#pragma unroll
        for (int c = 0; c < NCH; ++c) {
            short8 b0 = *(const short8*)(pB + c * 16);
            short8 b1 = *(const short8*)(pB + 32 * KCp + c * 16);
            short8 a0 = *(const short8*)(pA + c * 16);
            short8 a1 = *(const short8*)(pA + 32 * KCp + c * 16);
            acc00 = __builtin_amdgcn_mfma_f32_32x32x16_bf16(a0, b0, acc00, 0, 0, 0);
            acc01 = __builtin_amdgcn_mfma_f32_32x32x16_bf16(a0, b1, acc01, 0, 0, 0);
            acc10 = __builtin_amdgcn_mfma_f32_32x32x16_bf16(a1, b0, acc10, 0, 0, 0);
            acc11 = __builtin_amdgcn_mfma_f32_32x32x16_bf16(a1, b1, acc11, 0, 0, 0);
        }
        if (s + 1 < STOT) {
            storeLDS((s + 1) & 1, (s + 1) & 1);
            sync_lds();
        }
    }

    // epilogue: relu(acc + beta) -> bf16, channels-last padded store (R9 pattern per tile)
#pragma unroll
    for (int i = 0; i < 2; ++i) {
#pragma unroll
        for (int j = 0; j < 2; ++j) {
            const f32x16& a = (i == 0) ? (j == 0 ? acc00 : acc01) : (j == 0 ? acc10 : acc11);
            int vg2 = v_off + bys * 128 + wc * 64 + j * 32 + l31;
            int x = vg2 & (D - 1);
            int ry = vg2 >> lgD;
            int y = ry & (D - 1);
            int z = ry >> lgD;
            int cbase = co0 + wr * 64 + i * 32;
            size_t ob = (((size_t)(z + 1) * Xpo + (y + 1)) * Xpo + (x + 1)) * Co + cbase;
#pragma unroll
            for (int g = 0; g < 4; ++g) {
                int cb = 4 * lh + 8 * g;
                float4 bt = *(const float4*)(beta + cbase + cb);
                ushort4 u;
                u.x = f2bf(fmaxf(a[g * 4 + 0] + bt.x, 0.f));
                u.y = f2bf(fmaxf(a[g * 4 + 1] + bt.y, 0.f));
                u.z = f2bf(fmaxf(a[g * 4 + 2] + bt.z, 0.f));
                u.w = f2bf(fmaxf(a[g * 4 + 3] + bt.w, 0.f));
                *(ushort4*)(out + ob + cb) = u;
            }
        }
    }
}

// ---------------- BEV max over y: O6p (34,34,34,256) -> bev[(z*32+x)*256+c] f32 ----------------
__global__ __launch_bounds__(256) void bev_max_kernel(const unsigned short* __restrict__ feat,
                                                      float* __restrict__ bev) {
    int z = blockIdx.x >> 5;
    int x = blockIdx.x & 31;
    int c = threadIdx.x;
    const unsigned short* p = feat + ((((z + 1) * 34) + 1) * 34 + (x + 1)) * 256 + c;
    float mx = 0.f;  // post-ReLU values are >= 0
#pragma unroll
    for (int y = 0; y < 32; ++y) mx = fmaxf(mx, bf2f(p[y * 34 * 256]));
    bev[(z * 32 + x) * 256 + c] = mx;
}

// ---------------- bilinear resize 32x32 -> 200x200, half-pixel, edge clamp ----------------
__global__ __launch_bounds__(256) void resize_kernel(const float* __restrict__ bev,
                                                     float* __restrict__ out) {
    int i = blockIdx.x * 256 + threadIdx.x;
    if (i >= 256 * 200 * 200) return;
    int ox = i % 200;
    int t = i / 200;
    int oy = t % 200;
    int c = t / 200;
    const float sc = 32.0f / 200.0f;
    float fy = (oy + 0.5f) * sc - 0.5f;
    float fx = (ox + 0.5f) * sc - 0.5f;
    float fy0 = floorf(fy), fx0 = floorf(fx);
    float ty = fy - fy0, tx = fx - fx0;
    int y0 = min(max((int)fy0, 0), 31), y1 = min(max((int)fy0 + 1, 0), 31);
    int x0 = min(max((int)fx0, 0), 31), x1 = min(max((int)fx0 + 1, 0), 31);
    float v00 = bev[(y0 * 32 + x0) * 256 + c], v01 = bev[(y0 * 32 + x1) * 256 + c];
    float v10 = bev[(y1 * 32 + x0) * 256 + c], v11 = bev[(y1 * 32 + x1) * 256 + c];
    float top = v00 + tx * (v01 - v00);
    float bot = v10 + tx * (v11 - v10);
    out[i] = top + ty * (bot - top);
}

extern "C" void kernel_launch(void* const* d_in, const int* in_sizes, int n_in,
                              void* d_out, int out_size, void* d_ws, size_t ws_size,
                              hipStream_t stream) {
    const float* points = (const float*)d_in[0];
    int N = in_sizes[0] / 4;
    const float *W[6], *G[6], *B[6];
    for (int i = 0; i < 6; ++i) {
        W[i] = (const float*)d_in[1 + 3 * i];
        G[i] = (const float*)d_in[2 + 3 * i];
        B[i] = (const float*)d_in[3 + 3 * i];
    }

    // ---- workspace layout (bytes), peak ~145 MiB ----
    char* ws = (char*)d_ws;
    const size_t MiB = 1ull << 20;
    unsigned short* gridH = (unsigned short*)(ws);               // f16 (130^3,4) = 17,576,000 B
    int* cnt = (int*)(ws + 17580032);                            // 512 ints (gap before 18 MiB)
    int* off = cnt + 512;
    int* cur = off + 512;
    float4* sorted = (float4*)(ws + 18 * MiB);                   // 32 MB, dead before O1s use
    unsigned short* O1s = (unsigned short*)(ws + 18 * MiB);      // 65*130*130*32*2 = 70,304,000
    unsigned short* O2p = (unsigned short*)(ws + 104 * MiB);     // 66^3*64*2 = 36,799,488
    unsigned short* O3p = (unsigned short*)(ws);                 // 36,799,488 (over dead gridH/O1s-head)
    unsigned short* O4p = (unsigned short*)(ws + 37 * MiB);      // 34^3*128*2 = 10,061,824
    unsigned short* O5p = (unsigned short*)(ws + 48 * MiB);      // 10,061,824
    unsigned short* O6p = (unsigned short*)(ws + 59 * MiB);      // 34^3*256*2 = 20,123,648
    float* bev = (float*)(ws + 80 * MiB);                        // 1,048,576
    unsigned short* wc1 = (unsigned short*)(ws + 140 * MiB);     // 9*32*16*2 = 9,216
    unsigned short* wb2 = (unsigned short*)(ws + 140 * MiB + 16384);
    unsigned short* wb3 = wb2 + 27 * 64 * 32;
    unsigned short* wb4 = wb3 + 27 * 64 * 64;
    unsigned short* wb5 = wb4 + 27 * 128 * 64;
    unsigned short* wb6 = wb5 + 27 * 128 * 128;

    // weight repacks (independent of activations)
    repack_w1m<<<18, 256, 0, stream>>>(W[0], G[0], wc1);
    repack_w<<<216, 256, 0, stream>>>(W[1], G[1], wb2, 64, 32);
    repack_w<<<432, 256, 0, stream>>>(W[2], G[2], wb3, 64, 64);
    repack_w<<<864, 256, 0, stream>>>(W[3], G[3], wb4, 128, 64);
    repack_w<<<1728, 256, 0, stream>>>(W[4], G[4], wb5, 128, 128);
    repack_w<<<3456, 256, 0, stream>>>(W[5], G[5], wb6, 256, 128);

    // voxelize: bin -> scan -> sort -> LDS accumulate (no global atomics).
    pad_zero<<<pad_blocks(130, 130, 4), 256, 0, stream>>>(gridH, 130, 130, 4);
    hipMemsetAsync(cnt, 0, 2048, stream);
    pad_zero<<<pad_blocks(66, 66, 64), 256, 0, stream>>>(O2p, 66, 66, 64);
    vox_count<<<1024, 256, 0, stream>>>((const float4*)points, cnt, N);
    vox_scan<<<1, 512, 0, stream>>>(cnt, off, cur);
    vox_scatter<<<(N + 4095) / 4096, 256, 0, stream>>>((const float4*)points, cur, sorted, N);
    vox_accum<<<512, 256, 0, stream>>>(sorted, off, cnt, (__half2*)gridH);

    // conv1/conv2 in two z-slabs (O1s holds 65 padded-z rows); sorted is dead now.
    pad_zero<<<pad_blocks(130, 65, 32), 256, 0, stream>>>(O1s, 130, 65, 32);
    conv1_mfma<<<8192, 256, 0, stream>>>(gridH, wc1, B[0], O1s, 0, 1);
    conv_mfma<32, 32, 2><<<dim3(1, 1024), 256, 0, stream>>>(O1s, wb2, B[1], O2p, 64, 6, 130, 66, 64, 0, 0);
    conv1_mfma<<<8320, 256, 0, stream>>>(gridH, wc1, B[0], O1s, 63, 0);
    conv_mfma<32, 32, 2><<<dim3(1, 1024), 256, 0, stream>>>(O1s, wb2, B[1], O2p, 64, 6, 130, 66, 64, 64, 131072);

    // remaining buffers become free only after conv2-h2; shells only (interiors fully written)
    pad_zero<<<pad_blocks(66, 66, 64), 256, 0, stream>>>(O3p, 66, 66, 64);
    pad_zero<<<pad_blocks(34, 34, 128), 256, 0, stream>>>(O4p, 34, 34, 128);
    pad_zero<<<pad_blocks(34, 34, 128), 256, 0, stream>>>(O5p, 34, 34, 128);
    pad_zero<<<pad_blocks(34, 34, 256), 256, 0, stream>>>(O6p, 34, 34, 256);

    // conv3: 64->64, s1, 64^3  (R9 proven path)
    conv_mfma<64, 64, 1><<<dim3(1, 2048), 256, 0, stream>>>(O2p, wb3, B[2], O3p, 64, 6, 66, 66, 64, 0, 0);
    // conv4: 64->128, s2, 64^3 -> 32^3  (wide 128co x 128vox)
    conv_mfma_w<64, 2><<<dim3(1, 256), 256, 0, stream>>>(O3p, wb4, B[3], O4p, 32, 5, 66, 34, 128, 0, 0);
    // conv5: 128->128, s1, 32^3
    conv_mfma_w<128, 1><<<dim3(1, 256), 256, 0, stream>>>(O4p, wb5, B[4], O5p, 32, 5, 34, 34, 128, 0, 0);
    // conv6: 128->256, s1, 32^3
    conv_mfma_w<128, 1><<<dim3(2, 256), 256, 0, stream>>>(O5p, wb6, B[5], O6p, 32, 5, 34, 34, 256, 0, 0);

    bev_max_kernel<<<1024, 256, 0, stream>>>(O6p, bev);
    resize_kernel<<<40000, 256, 0, stream>>>(bev, (float*)d_out);
}